// Round 4
// baseline (1173.583 us; speedup 1.0000x reference)
//
#include <hip/hip_runtime.h>
#include <cstdint>

typedef unsigned short u16;
typedef unsigned long long u64;
typedef short short8 __attribute__((ext_vector_type(8)));
typedef float f32x4 __attribute__((ext_vector_type(4)));

#define D_DIM 192
#define M_PROT 128
#define KCOLS 256
#define GRID_P 512
#define BLK 512
#define CHUNK_ROWS 64
#define XSTRIDE 200   // u16 per x-row in LDS; 100 dwords -> 2-way banks on reads (free)

__device__ __forceinline__ float newton_rsqrt(float ss) {
    float m = fmaxf(ss, 1e-12f);
    float r = rsqrtf(m);
    r = r * (1.5f - 0.5f * m * r * r);
    return r;
}
__device__ __forceinline__ float fast_rcp(float x) {
    float r = __builtin_amdgcn_rcpf(x);
    return r * (2.0f - x * r);
}
__device__ __forceinline__ float bf2f(u16 u) {
    return __uint_as_float(((uint32_t)u) << 16);
}
// split fp32 -> bf16 hi (RNE) + bf16 lo (trunc of exact residual)
__device__ __forceinline__ void split1(float f, uint32_t& h, uint32_t& l) {
    uint32_t u = __float_as_uint(f);
    uint32_t uh = (u + 0x7FFFu + ((u >> 16) & 1u)) & 0xFFFF0000u;
    h = uh >> 16;
    l = __float_as_uint(f - __uint_as_float(uh)) >> 16;
}

// ---------------------------------------------------------------------------
__global__ void prep_kern(const float* __restrict__ lp, const float* __restrict__ gp,
                          u16* __restrict__ phi, u16* __restrict__ plo,
                          float* __restrict__ invnp, int* __restrict__ lastIdx) {
    int r = blockIdx.x, j = threadIdx.x;  // 256 x 64
    const float* src = (r < M_PROT) ? (lp + r * D_DIM) : (gp + (r - M_PROT) * D_DIM);
    float ss = 0.0f;
    for (int c = j; c < D_DIM; c += 64) {
        float f = src[c];
        ss = fmaf(f, f, ss);
        uint32_t h, l;
        split1(f, h, l);
        phi[r * D_DIM + c] = (u16)h;
        plo[r * D_DIM + c] = (u16)l;
    }
#pragma unroll
    for (int m = 1; m <= 32; m <<= 1) ss += __shfl_xor(ss, m);
    if (j == 0) {
        invnp[r] = newton_rsqrt(ss);
        if (r < M_PROT) lastIdx[r] = -1;
    }
}

// ---------------------------------------------------------------------------
__global__ __launch_bounds__(384) void glu_kern(const float* __restrict__ gp,
                                                const float* __restrict__ W,
                                                const float* __restrict__ b,
                                                float* __restrict__ gated) {
    __shared__ float grow[D_DIM];
    __shared__ float lin[2 * D_DIM];
    int m = blockIdx.x, j = threadIdx.x;
    if (j < D_DIM) grow[j] = gp[m * D_DIM + j];
    __syncthreads();
    float a = b[j];
    for (int k = 0; k < D_DIM; k++) a = fmaf(grow[k], W[k * 2 * D_DIM + j], a);
    lin[j] = a;
    __syncthreads();
    if (j < D_DIM) {
        float g = lin[j] * (1.0f / (1.0f + __expf(-lin[j + D_DIM])));
        gated[m * D_DIM + j] = g;
    }
}

// ---------------------------------------------------------------------------
__global__ void reduce_cols(const float* __restrict__ partials, float* __restrict__ outf, int G) {
    int j = threadIdx.x;
    float s = 0.0f;
    for (int g = 0; g < G; g++) s += partials[g * KCOLS + j];
    outf[j] = 1.0f / s;
}

// ---------------------------------------------------------------------------
// B(protos hi/lo) in registers per wave (32 cols), x staged in LDS per 64-row
// chunk with reg-prefetch. 2 blocks/CU so phases of the two blocks interleave.
template <int PASS>
__global__ __launch_bounds__(BLK, 4) void pass_kern(
    const float* __restrict__ x, const uint4* __restrict__ phiv, const uint4* __restrict__ plov,
    const float* __restrict__ invnp, const float* __restrict__ colfac,
    float* __restrict__ partials, int* __restrict__ lastIdx,
    const float* __restrict__ gated, float* __restrict__ outp, int nchunks) {
    __shared__ u16 xhiS[CHUNK_ROWS * XSTRIDE];
    __shared__ u16 xloS[CHUNK_ROWS * XSTRIDE];
    __shared__ float xss[CHUNK_ROWS];
    __shared__ float rsum[CHUNK_ROWS];
    __shared__ u64 bestL[CHUNK_ROWS];
    __shared__ u64 bestG[CHUNK_ROWS];

    const int tid = threadIdx.x;
    const int lane = tid & 63;
    const int wave = tid >> 6;
    const int quad = lane >> 4;
    const int lcol = lane & 15;
    const int c0 = wave * 32;
    const int srow = tid >> 3;   // staging: this thread's row
    const int scg = tid & 7;     // staging: col-group (24 cols)

    // --- B fragments in registers: wave's 32 proto cols, all K, hi+lo ---
    uint4 Bhi[2][6], Blo[2][6];
#pragma unroll
    for (int t = 0; t < 2; t++) {
        int prow = c0 + t * 16 + lcol;
#pragma unroll
        for (int kk = 0; kk < 6; kk++) {
            int idx = prow * 24 + kk * 4 + quad;
            Bhi[t][kk] = phiv[idx];
            Blo[t][kk] = plov[idx];
        }
    }
    float pnf[2], cf[2];
#pragma unroll
    for (int t = 0; t < 2; t++) {
        pnf[t] = invnp[c0 + t * 16 + lcol];
        if constexpr (PASS >= 2) cf[t] = colfac[c0 + t * 16 + lcol];
        else cf[t] = 1.0f;
    }
    float colpart[2] = {0.0f, 0.0f};

    // prefetch chunk 0: 6 float4 = 24 contiguous cols of row srow
    float4 st[6];
    int chunk = blockIdx.x;
    {
        const float4* src = (const float4*)(x + (size_t)chunk * CHUNK_ROWS * D_DIM) +
                            srow * 48 + scg * 6;
#pragma unroll
        for (int j = 0; j < 6; j++) st[j] = src[j];
    }

    for (; chunk < nchunks; chunk += gridDim.x) {
        __syncthreads();  // S_a: previous chunk fully consumed
        if (tid < CHUNK_ROWS) {
            if constexpr (PASS <= 3) rsum[tid] = 0.0f;
            else { bestL[tid] = 0ull; bestG[tid] = 0ull; }
        }
        // stage x chunk (split to bf16 hi/lo) + row sumsq via 8-lane shfl
        {
            float ssq = 0.0f;
            u16* bh = xhiS + srow * XSTRIDE + scg * 24;
            u16* bl = xloS + srow * XSTRIDE + scg * 24;
#pragma unroll
            for (int j = 0; j < 6; j++) {
                float4 v = st[j];
                ssq = fmaf(v.x, v.x, ssq);
                ssq = fmaf(v.y, v.y, ssq);
                ssq = fmaf(v.z, v.z, ssq);
                ssq = fmaf(v.w, v.w, ssq);
                uint32_t h0, l0, h1, l1, h2, l2, h3, l3;
                split1(v.x, h0, l0); split1(v.y, h1, l1);
                split1(v.z, h2, l2); split1(v.w, h3, l3);
                uint2 hp = {h0 | (h1 << 16), h2 | (h3 << 16)};
                uint2 lq = {l0 | (l1 << 16), l2 | (l3 << 16)};
                *(uint2*)(bh + j * 4) = hp;
                *(uint2*)(bl + j * 4) = lq;
            }
            ssq += __shfl_xor(ssq, 1);
            ssq += __shfl_xor(ssq, 2);
            ssq += __shfl_xor(ssq, 4);
            if (scg == 0) xss[srow] = ssq;
        }
        {   // prefetch next chunk while this one computes
            int nc = chunk + gridDim.x;
            if (nc < nchunks) {
                const float4* src = (const float4*)(x + (size_t)nc * CHUNK_ROWS * D_DIM) +
                                    srow * 48 + scg * 6;
#pragma unroll
                for (int j = 0; j < 6; j++) st[j] = src[j];
            }
        }
        __syncthreads();  // S_b: staging visible

        f32x4 E[2][4];
#pragma unroll
        for (int s = 0; s < 4; s++) {
            f32x4 acc[2][2] = {{{}, {}}, {{}, {}}};  // [coltile][kk parity]
#pragma unroll
            for (int kk = 0; kk < 6; kk++) {
                const int p = kk & 1;
                int off = (s * 16 + lcol) * XSTRIDE + kk * 32 + quad * 8;
                uint4 hraw = *(const uint4*)(xhiS + off);
                uint4 lraw = *(const uint4*)(xloS + off);
                short8 ah = __builtin_bit_cast(short8, hraw);
                short8 al = __builtin_bit_cast(short8, lraw);
                short8 b0h = __builtin_bit_cast(short8, Bhi[0][kk]);
                short8 b0l = __builtin_bit_cast(short8, Blo[0][kk]);
                short8 b1h = __builtin_bit_cast(short8, Bhi[1][kk]);
                short8 b1l = __builtin_bit_cast(short8, Blo[1][kk]);
                acc[0][p] = __builtin_amdgcn_mfma_f32_16x16x32_bf16(ah, b0h, acc[0][p], 0, 0, 0);
                acc[1][p] = __builtin_amdgcn_mfma_f32_16x16x32_bf16(ah, b1h, acc[1][p], 0, 0, 0);
                acc[0][p] = __builtin_amdgcn_mfma_f32_16x16x32_bf16(ah, b0l, acc[0][p], 0, 0, 0);
                acc[1][p] = __builtin_amdgcn_mfma_f32_16x16x32_bf16(ah, b1l, acc[1][p], 0, 0, 0);
                acc[0][p] = __builtin_amdgcn_mfma_f32_16x16x32_bf16(al, b0h, acc[0][p], 0, 0, 0);
                acc[1][p] = __builtin_amdgcn_mfma_f32_16x16x32_bf16(al, b1h, acc[1][p], 0, 0, 0);
            }
            const int rowb = s * 16 + quad * 4;
            float invnx[4];
#pragma unroll
            for (int r = 0; r < 4; r++) invnx[r] = newton_rsqrt(xss[rowb + r]);
#pragma unroll
            for (int r = 0; r < 4; r++) {
                E[0][s][r] = __expf((acc[0][0][r] + acc[0][1][r]) * invnx[r] * pnf[0] * 20.0f);
                E[1][s][r] = __expf((acc[1][0][r] + acc[1][1][r]) * invnx[r] * pnf[1] * 20.0f);
            }
            if constexpr (PASS <= 3) {
#pragma unroll
                for (int r = 0; r < 4; r++) {
                    float p = E[0][s][r] * cf[0] + E[1][s][r] * cf[1];
                    p += __shfl_xor(p, 1);
                    p += __shfl_xor(p, 2);
                    p += __shfl_xor(p, 4);
                    p += __shfl_xor(p, 8);
                    if (lcol == 0) atomicAdd(&rsum[rowb + r], p);
                }
            } else {
#pragma unroll
                for (int r = 0; r < 4; r++) {
                    float v0 = E[0][s][r] * cf[0];
                    float v1 = E[1][s][r] * cf[1];
                    float v; int col;
                    if (v1 > v0) { v = v1; col = c0 + 16 + lcol; }
                    else         { v = v0; col = c0 + lcol; }
                    u64 key = ((u64)__float_as_uint(v) << 32) | (u64)(255 - col);
#pragma unroll
                    for (int m = 1; m <= 8; m <<= 1) {
                        u64 ok = __shfl_xor((unsigned long long)key, m);
                        if (ok > key) key = ok;
                    }
                    if (lcol == 0) {
                        u64* bst = (wave < 4) ? bestL : bestG;
                        atomicMax(&bst[rowb + r], key);
                    }
                }
            }
        }
        __syncthreads();  // S_c: rsum / best complete

        if constexpr (PASS <= 3) {
#pragma unroll
            for (int s = 0; s < 4; s++) {
                const int rowb = s * 16 + quad * 4;
#pragma unroll
                for (int r = 0; r < 4; r++) {
                    float rv = fast_rcp(rsum[rowb + r]);
                    colpart[0] = fmaf(E[0][s][r], rv, colpart[0]);
                    colpart[1] = fmaf(E[1][s][r], rv, colpart[1]);
                }
            }
        } else {
            if (tid < CHUNK_ROWS) {
                int colL = 255 - (int)(bestL[tid] & 0xFFFFFFFFull);
                atomicMax(&lastIdx[colL], chunk * CHUNK_ROWS + tid);
            }
#pragma unroll
            for (int rr = 0; rr < 8; rr++) {
                const int row = wave * 8 + rr;
                const int grow = chunk * CHUNK_ROWS + row;
                const int ga = (255 - (int)(bestG[row] & 0xFFFFFFFFull)) - 128;
                const float* gr = gated + ga * D_DIM;
                float v[3];
                float ss = 0.0f;
#pragma unroll
                for (int q = 0; q < 3; q++) {
                    int c = lane + q * 64;
                    float xf = bf2f(xhiS[row * XSTRIDE + c]) + bf2f(xloS[row * XSTRIDE + c]);
                    float vv = 0.5f * (gr[c] + xf);
                    v[q] = vv;
                    ss = fmaf(vv, vv, ss);
                }
                ss += __shfl_xor(ss, 1);
                ss += __shfl_xor(ss, 2);
                ss += __shfl_xor(ss, 4);
                ss += __shfl_xor(ss, 8);
                ss += __shfl_xor(ss, 16);
                ss += __shfl_xor(ss, 32);
                float sc = newton_rsqrt(ss);
                float* orow = outp + (size_t)grow * D_DIM;
#pragma unroll
                for (int q = 0; q < 3; q++) orow[lane + q * 64] = v[q] * sc;
            }
        }
    }

    if constexpr (PASS <= 3) {
#pragma unroll
        for (int t = 0; t < 2; t++) {
            colpart[t] += __shfl_xor(colpart[t], 16);
            colpart[t] += __shfl_xor(colpart[t], 32);
        }
        if (lane < 16) {
            partials[blockIdx.x * KCOLS + c0 + lcol] = colpart[0];
            partials[blockIdx.x * KCOLS + c0 + 16 + lcol] = colpart[1];
        }
    }
}

// ---------------------------------------------------------------------------
__global__ void final_local(const float* __restrict__ lp, const float* __restrict__ x,
                            const int* __restrict__ lastIdx, float* __restrict__ outL) {
    int m = blockIdx.x;   // 128
    int c = threadIdx.x;  // 192
    int idx = lastIdx[m];
    float v = lp[m * D_DIM + c];
    if (idx >= 0) v = 0.96f * v + (float)(1.0 - 0.96) * x[(size_t)idx * D_DIM + c];
    outL[m * D_DIM + c] = v;
}

// ---------------------------------------------------------------------------
extern "C" void kernel_launch(void* const* d_in, const int* in_sizes, int n_in,
                              void* d_out, int out_size, void* d_ws, size_t ws_size,
                              hipStream_t stream) {
    const float* x = (const float*)d_in[0];
    const float* lp = (const float*)d_in[1];
    const float* gp = (const float*)d_in[2];
    const float* W = (const float*)d_in[3];
    const float* b = (const float*)d_in[4];
    float* out = (float*)d_out;
    const int nrows = in_sizes[0] / D_DIM;  // 131072
    const int nchunks = nrows / CHUNK_ROWS; // 2048

    char* wsb = (char*)d_ws;
    float* invnp = (float*)(wsb + 0);
    float* g1 = (float*)(wsb + 1024);
    float* g2 = (float*)(wsb + 2048);
    float* g3 = (float*)(wsb + 3072);
    int* lastIdx = (int*)(wsb + 4096);
    float* gated = (float*)(wsb + 8192);      // 128*192 f
    u16* phi = (u16*)(wsb + 106496);          // 256*192 u16
    u16* plo = (u16*)(wsb + 204800);          // 256*192 u16
    float* partials = (float*)(wsb + 303104); // 512*256 f

    const uint4* phiv = (const uint4*)phi;
    const uint4* plov = (const uint4*)plo;

    prep_kern<<<256, 64, 0, stream>>>(lp, gp, phi, plo, invnp, lastIdx);
    glu_kern<<<128, 384, 0, stream>>>(gp, W, b, gated);
    pass_kern<1><<<GRID_P, BLK, 0, stream>>>(x, phiv, plov, invnp, nullptr, partials,
                                             nullptr, nullptr, nullptr, nchunks);
    reduce_cols<<<1, 256, 0, stream>>>(partials, g1, GRID_P);
    pass_kern<2><<<GRID_P, BLK, 0, stream>>>(x, phiv, plov, invnp, g1, partials,
                                             nullptr, nullptr, nullptr, nchunks);
    reduce_cols<<<1, 256, 0, stream>>>(partials, g2, GRID_P);
    pass_kern<3><<<GRID_P, BLK, 0, stream>>>(x, phiv, plov, invnp, g2, partials,
                                             nullptr, nullptr, nullptr, nchunks);
    reduce_cols<<<1, 256, 0, stream>>>(partials, g3, GRID_P);
    pass_kern<4><<<GRID_P, BLK, 0, stream>>>(x, phiv, plov, invnp, g3, nullptr,
                                             lastIdx, gated, out, nchunks);
    final_local<<<128, 192, 0, stream>>>(lp, x, lastIdx, out + (size_t)nrows * D_DIM);
}

// Round 5
// 575.333 us; speedup vs baseline: 2.0398x; 2.0398x over previous
//
#include <hip/hip_runtime.h>
#include <cstdint>

typedef unsigned short u16;
typedef unsigned long long u64;
typedef short short8 __attribute__((ext_vector_type(8)));
typedef float f32x4 __attribute__((ext_vector_type(4)));

#define D_DIM 192
#define M_PROT 128
#define KCOLS 256
#define GRID_P 256
#define BLK 1024
#define CHUNK_ROWS 64
#define XSTRIDE 200   // u16 per x-row in LDS; 100 dwords -> 2-way banks on b128 reads (free)

__device__ __forceinline__ float newton_rsqrt(float ss) {
    float m = fmaxf(ss, 1e-12f);
    float r = rsqrtf(m);
    r = r * (1.5f - 0.5f * m * r * r);
    return r;
}
__device__ __forceinline__ float fast_rcp(float x) {
    float r = __builtin_amdgcn_rcpf(x);
    return r * (2.0f - x * r);
}
__device__ __forceinline__ float bf2f(u16 u) {
    return __uint_as_float(((uint32_t)u) << 16);
}
// split fp32 -> bf16 hi (RNE) + bf16 lo (trunc of exact residual)
__device__ __forceinline__ void split1(float f, uint32_t& h, uint32_t& l) {
    uint32_t u = __float_as_uint(f);
    uint32_t uh = (u + 0x7FFFu + ((u >> 16) & 1u)) & 0xFFFF0000u;
    h = uh >> 16;
    l = __float_as_uint(f - __uint_as_float(uh)) >> 16;
}

// ---------------------------------------------------------------------------
__global__ void prep_kern(const float* __restrict__ lp, const float* __restrict__ gp,
                          u16* __restrict__ phi, u16* __restrict__ plo,
                          float* __restrict__ invnp, int* __restrict__ lastIdx) {
    int r = blockIdx.x, j = threadIdx.x;  // 256 x 64
    const float* src = (r < M_PROT) ? (lp + r * D_DIM) : (gp + (r - M_PROT) * D_DIM);
    float ss = 0.0f;
    for (int c = j; c < D_DIM; c += 64) {
        float f = src[c];
        ss = fmaf(f, f, ss);
        uint32_t h, l;
        split1(f, h, l);
        phi[r * D_DIM + c] = (u16)h;
        plo[r * D_DIM + c] = (u16)l;
    }
#pragma unroll
    for (int m = 1; m <= 32; m <<= 1) ss += __shfl_xor(ss, m);
    if (j == 0) {
        invnp[r] = newton_rsqrt(ss);
        if (r < M_PROT) lastIdx[r] = -1;
    }
}

// ---------------------------------------------------------------------------
__global__ __launch_bounds__(384) void glu_kern(const float* __restrict__ gp,
                                                const float* __restrict__ W,
                                                const float* __restrict__ b,
                                                float* __restrict__ gated) {
    __shared__ float grow[D_DIM];
    __shared__ float lin[2 * D_DIM];
    int m = blockIdx.x, j = threadIdx.x;
    if (j < D_DIM) grow[j] = gp[m * D_DIM + j];
    __syncthreads();
    float a = b[j];
    for (int k = 0; k < D_DIM; k++) a = fmaf(grow[k], W[k * 2 * D_DIM + j], a);
    lin[j] = a;
    __syncthreads();
    if (j < D_DIM) {
        float g = lin[j] * (1.0f / (1.0f + __expf(-lin[j + D_DIM])));
        gated[m * D_DIM + j] = g;
    }
}

// ---------------------------------------------------------------------------
__global__ __launch_bounds__(1024) void reduce_cols(const float* __restrict__ partials,
                                                    float* __restrict__ outf, int G) {
    __shared__ float acc[4][KCOLS];
    int j = threadIdx.x & 255;
    int sl = threadIdx.x >> 8;
    float s = 0.0f;
    for (int g = sl; g < G; g += 4) s += partials[g * KCOLS + j];
    acc[sl][j] = s;
    __syncthreads();
    if (threadIdx.x < KCOLS) {
        int jj = threadIdx.x;
        outf[jj] = 1.0f / (acc[0][jj] + acc[1][jj] + acc[2][jj] + acc[3][jj]);
    }
}

// ---------------------------------------------------------------------------
// 16 waves x 16 proto-cols each (B hi/lo in 48 regs/wave), x staged in LDS per
// 64-row chunk with reg-prefetch. ~120 VGPR -> 4 waves/SIMD, no spill.
template <int PASS>
__global__ __launch_bounds__(BLK, 4) void pass_kern(
    const float* __restrict__ x, const uint4* __restrict__ phiv, const uint4* __restrict__ plov,
    const float* __restrict__ invnp, const float* __restrict__ colfac,
    float* __restrict__ partials, int* __restrict__ lastIdx,
    const float* __restrict__ gated, float* __restrict__ outp, int nchunks) {
    __shared__ u16 xhiS[CHUNK_ROWS * XSTRIDE];
    __shared__ u16 xloS[CHUNK_ROWS * XSTRIDE];
    __shared__ float xss[CHUNK_ROWS];
    __shared__ float rsum[2][CHUNK_ROWS];
    __shared__ u64 bestL[2][CHUNK_ROWS];
    __shared__ u64 bestG[2][CHUNK_ROWS];

    const int tid = threadIdx.x;
    const int lane = tid & 63;
    const int wave = tid >> 6;        // 0..15: proto col-tile
    const int quad = lane >> 4;
    const int lcol = lane & 15;
    const int srow = tid >> 4;        // staging: row 0..63
    const int scg = tid & 15;         // staging: col-group (12 floats)

    // --- B fragments in registers: this wave's 16 proto cols, all K, hi+lo ---
    uint4 Bhi[6], Blo[6];
    {
        int prow = wave * 16 + lcol;
#pragma unroll
        for (int kk = 0; kk < 6; kk++) {
            int idx = prow * 24 + kk * 4 + quad;
            Bhi[kk] = phiv[idx];
            Blo[kk] = plov[idx];
        }
    }
    const float pnf = invnp[wave * 16 + lcol];
    const float cfv = (PASS >= 2) ? colfac[wave * 16 + lcol] : 1.0f;
    float colpart = 0.0f;

    // prefetch chunk 0: 3 float4 = 12 contiguous cols of row srow
    float4 st[3];
    int chunk = blockIdx.x;
    {
        const float4* src = (const float4*)(x + (size_t)chunk * CHUNK_ROWS * D_DIM +
                                            srow * D_DIM + scg * 12);
#pragma unroll
        for (int j = 0; j < 3; j++) st[j] = src[j];
    }

    int it = 0;
    for (; chunk < nchunks; chunk += gridDim.x, it++) {
        const int p = it & 1;
        if constexpr (PASS == 4) __syncthreads();  // S_a: epilogue's xhiS reads done
        // staging: zero this parity's reduce buffers + write split x + row ssq
        if (tid < CHUNK_ROWS) {
            if constexpr (PASS <= 3) rsum[p][tid] = 0.0f;
            else { bestL[p][tid] = 0ull; bestG[p][tid] = 0ull; }
        }
        {
            float ssq = 0.0f;
            u16* bh = xhiS + srow * XSTRIDE + scg * 12;
            u16* bl = xloS + srow * XSTRIDE + scg * 12;
#pragma unroll
            for (int j = 0; j < 3; j++) {
                float4 v = st[j];
                ssq = fmaf(v.x, v.x, ssq);
                ssq = fmaf(v.y, v.y, ssq);
                ssq = fmaf(v.z, v.z, ssq);
                ssq = fmaf(v.w, v.w, ssq);
                uint32_t h0, l0, h1, l1, h2, l2, h3, l3;
                split1(v.x, h0, l0); split1(v.y, h1, l1);
                split1(v.z, h2, l2); split1(v.w, h3, l3);
                uint2 hp = {h0 | (h1 << 16), h2 | (h3 << 16)};
                uint2 lq = {l0 | (l1 << 16), l2 | (l3 << 16)};
                *(uint2*)(bh + j * 4) = hp;
                *(uint2*)(bl + j * 4) = lq;
            }
            ssq += __shfl_xor(ssq, 1);
            ssq += __shfl_xor(ssq, 2);
            ssq += __shfl_xor(ssq, 4);
            ssq += __shfl_xor(ssq, 8);
            if (scg == 0) xss[srow] = ssq;
        }
        {   // prefetch next chunk while this one computes
            int nc = chunk + gridDim.x;
            if (nc < nchunks) {
                const float4* src = (const float4*)(x + (size_t)nc * CHUNK_ROWS * D_DIM +
                                                    srow * D_DIM + scg * 12);
#pragma unroll
                for (int j = 0; j < 3; j++) st[j] = src[j];
            }
        }
        __syncthreads();  // S_b: staging visible

        f32x4 E[4];
#pragma unroll
        for (int s = 0; s < 4; s++) {
            f32x4 a0 = {}, a1 = {};
#pragma unroll
            for (int kk = 0; kk < 6; kk++) {
                int off = (s * 16 + lcol) * XSTRIDE + kk * 32 + quad * 8;
                uint4 hraw = *(const uint4*)(xhiS + off);
                uint4 lraw = *(const uint4*)(xloS + off);
                short8 ah = __builtin_bit_cast(short8, hraw);
                short8 al = __builtin_bit_cast(short8, lraw);
                short8 bh = __builtin_bit_cast(short8, Bhi[kk]);
                short8 bl = __builtin_bit_cast(short8, Blo[kk]);
                if (kk & 1) {
                    a1 = __builtin_amdgcn_mfma_f32_16x16x32_bf16(ah, bh, a1, 0, 0, 0);
                    a1 = __builtin_amdgcn_mfma_f32_16x16x32_bf16(ah, bl, a1, 0, 0, 0);
                    a1 = __builtin_amdgcn_mfma_f32_16x16x32_bf16(al, bh, a1, 0, 0, 0);
                } else {
                    a0 = __builtin_amdgcn_mfma_f32_16x16x32_bf16(ah, bh, a0, 0, 0, 0);
                    a0 = __builtin_amdgcn_mfma_f32_16x16x32_bf16(ah, bl, a0, 0, 0, 0);
                    a0 = __builtin_amdgcn_mfma_f32_16x16x32_bf16(al, bh, a0, 0, 0, 0);
                }
            }
            const int rowb = s * 16 + quad * 4;
#pragma unroll
            for (int r = 0; r < 4; r++) {
                float invnx = newton_rsqrt(xss[rowb + r]);
                E[s][r] = __expf((a0[r] + a1[r]) * invnx * pnf * 20.0f);
            }
            if constexpr (PASS <= 3) {
#pragma unroll
                for (int r = 0; r < 4; r++) {
                    float pe = E[s][r] * cfv;
                    pe += __shfl_xor(pe, 1);
                    pe += __shfl_xor(pe, 2);
                    pe += __shfl_xor(pe, 4);
                    pe += __shfl_xor(pe, 8);
                    if (lcol == 0) atomicAdd(&rsum[p][rowb + r], pe);
                }
            } else {
#pragma unroll
                for (int r = 0; r < 4; r++) {
                    float v = E[s][r] * cfv;
                    int col = wave * 16 + lcol;
                    u64 key = ((u64)__float_as_uint(v) << 32) | (u64)(255 - col);
#pragma unroll
                    for (int m = 1; m <= 8; m <<= 1) {
                        u64 ok = __shfl_xor((unsigned long long)key, m);
                        if (ok > key) key = ok;
                    }
                    if (lcol == 0) {
                        u64* bst = (wave < 8) ? bestL[p] : bestG[p];
                        atomicMax(&bst[rowb + r], key);
                    }
                }
            }
        }
        __syncthreads();  // S_c: rsum / best complete

        if constexpr (PASS <= 3) {
#pragma unroll
            for (int s = 0; s < 4; s++) {
                const int rowb = s * 16 + quad * 4;
#pragma unroll
                for (int r = 0; r < 4; r++) {
                    float rv = fast_rcp(rsum[p][rowb + r]);
                    colpart = fmaf(E[s][r], rv, colpart);
                }
            }
        } else {
            if (tid < CHUNK_ROWS) {
                int colL = 255 - (int)(bestL[p][tid] & 0xFFFFFFFFull);
                atomicMax(&lastIdx[colL], chunk * CHUNK_ROWS + tid);
            }
#pragma unroll
            for (int rr = 0; rr < 4; rr++) {
                const int row = wave * 4 + rr;
                const int grow = chunk * CHUNK_ROWS + row;
                const int ga = (255 - (int)(bestG[p][row] & 0xFFFFFFFFull)) - 128;
                const float* gr = gated + ga * D_DIM;
                float v[3];
                float ss = 0.0f;
#pragma unroll
                for (int q = 0; q < 3; q++) {
                    int c = lane + q * 64;
                    float xf = bf2f(xhiS[row * XSTRIDE + c]) + bf2f(xloS[row * XSTRIDE + c]);
                    float vv = 0.5f * (gr[c] + xf);
                    v[q] = vv;
                    ss = fmaf(vv, vv, ss);
                }
                ss += __shfl_xor(ss, 1);
                ss += __shfl_xor(ss, 2);
                ss += __shfl_xor(ss, 4);
                ss += __shfl_xor(ss, 8);
                ss += __shfl_xor(ss, 16);
                ss += __shfl_xor(ss, 32);
                float sc = newton_rsqrt(ss);
                float* orow = outp + (size_t)grow * D_DIM;
#pragma unroll
                for (int q = 0; q < 3; q++) orow[lane + q * 64] = v[q] * sc;
            }
        }
    }

    if constexpr (PASS <= 3) {
        colpart += __shfl_xor(colpart, 16);
        colpart += __shfl_xor(colpart, 32);
        if (lane < 16) partials[blockIdx.x * KCOLS + wave * 16 + lcol] = colpart;
    }
}

// ---------------------------------------------------------------------------
__global__ void final_local(const float* __restrict__ lp, const float* __restrict__ x,
                            const int* __restrict__ lastIdx, float* __restrict__ outL) {
    int m = blockIdx.x;   // 128
    int c = threadIdx.x;  // 192
    int idx = lastIdx[m];
    float v = lp[m * D_DIM + c];
    if (idx >= 0) v = 0.96f * v + (float)(1.0 - 0.96) * x[(size_t)idx * D_DIM + c];
    outL[m * D_DIM + c] = v;
}

// ---------------------------------------------------------------------------
extern "C" void kernel_launch(void* const* d_in, const int* in_sizes, int n_in,
                              void* d_out, int out_size, void* d_ws, size_t ws_size,
                              hipStream_t stream) {
    const float* x = (const float*)d_in[0];
    const float* lp = (const float*)d_in[1];
    const float* gp = (const float*)d_in[2];
    const float* W = (const float*)d_in[3];
    const float* b = (const float*)d_in[4];
    float* out = (float*)d_out;
    const int nrows = in_sizes[0] / D_DIM;  // 131072
    const int nchunks = nrows / CHUNK_ROWS; // 2048

    char* wsb = (char*)d_ws;
    float* invnp = (float*)(wsb + 0);
    float* g1 = (float*)(wsb + 1024);
    float* g2 = (float*)(wsb + 2048);
    float* g3 = (float*)(wsb + 3072);
    int* lastIdx = (int*)(wsb + 4096);
    float* gated = (float*)(wsb + 8192);      // 128*192 f
    u16* phi = (u16*)(wsb + 106496);          // 256*192 u16
    u16* plo = (u16*)(wsb + 204800);          // 256*192 u16
    float* partials = (float*)(wsb + 303104); // 256*256 f

    const uint4* phiv = (const uint4*)phi;
    const uint4* plov = (const uint4*)plo;

    prep_kern<<<256, 64, 0, stream>>>(lp, gp, phi, plo, invnp, lastIdx);
    glu_kern<<<128, 384, 0, stream>>>(gp, W, b, gated);
    pass_kern<1><<<GRID_P, BLK, 0, stream>>>(x, phiv, plov, invnp, nullptr, partials,
                                             nullptr, nullptr, nullptr, nchunks);
    reduce_cols<<<1, 1024, 0, stream>>>(partials, g1, GRID_P);
    pass_kern<2><<<GRID_P, BLK, 0, stream>>>(x, phiv, plov, invnp, g1, partials,
                                             nullptr, nullptr, nullptr, nchunks);
    reduce_cols<<<1, 1024, 0, stream>>>(partials, g2, GRID_P);
    pass_kern<3><<<GRID_P, BLK, 0, stream>>>(x, phiv, plov, invnp, g2, partials,
                                             nullptr, nullptr, nullptr, nchunks);
    reduce_cols<<<1, 1024, 0, stream>>>(partials, g3, GRID_P);
    pass_kern<4><<<GRID_P, BLK, 0, stream>>>(x, phiv, plov, invnp, g3, nullptr,
                                             lastIdx, gated, out, nchunks);
    final_local<<<128, 192, 0, stream>>>(lp, x, lastIdx, out + (size_t)nrows * D_DIM);
}